// Round 4
// baseline (103.598 us; speedup 1.0000x reference)
//
#include <hip/hip_runtime.h>
#include <math.h>

#define NB 8
#define NN 1000
#define NV 10000
#define NSEG 40                  // cull source blocks (256 v1 points each)
#define NSEG2 20                 // match super-segments (2 source segs each)
#define SEGCAP 256               // <=256 survivors per (block,batch), structural
#define NEB 1024                 // padded electrodes per batch

// render region: all contributions provably in X,Y in [90,166]
// (ecc<=12 -> |c-128|<=34.14 -> f in [93,162] -> X in [90,166])
#define RB0 88                   // region origin
#define RSZ 80                   // region size (80x80)
#define RPX 6400                 // RSZ*RSZ
#define NEBLK 16                 // electrode blocks per batch (64 elec each)

// ---- workspace layout (float offsets), ~5.1 MB ----
#define WS_CNT  0                // 320 ints: per (seg 40, batch 8) survivor counts
#define WS_EPOS 512              // 8192 x float4 (px,py,pz, C|P|^2)
#define WS_CPOS 33280            // 8 x 10240 x float4 (-2Cx,-2Cy,-2Cz, C|q|^2)
#define WS_CPRF 360960           // 8 x 10240 x float2 (pol, ecc)
#define WS_PART 524800           // 8 x 20 x 1024 x float4 partials
#define WS_MAX  1212928          // 8 per-b max
// RPART overlays CPOS/CPRF/PART (all dead before k_render): 128 x 6400 floats
#define WS_RPART 33280           // ends 852480 (safe, PART consumed by k_render)
#define WS_RSUM  1212936         // 8 x 6400 region sums

// Shared per-batch setup: R[9], center[3], shank, halfext[3] (16 floats x 8 b).
__device__ __forceinline__ void batch_setup(const float* params, const float* start_loc,
                                            const float* lut, const float* agrid,
                                            const float* bgrid, float* sst, int t) {
    if (t < NB) {
        int b = t;
        float alpha = params[b*4+0], beta = params[b*4+1];
        float off   = params[b*4+2], shank = params[b*4+3];
        const float D2R = 0.017453292519943295f;
        float a = alpha*D2R, bb = beta*D2R;
        float ca = cosf(a), sa = sinf(a), cb = cosf(bb), sb = sinf(bb);
        float r00=cb,     r01=0.f, r02=sb;
        float r10=sa*sb,  r11=ca,  r12=-sa*cb;
        float r20=-ca*sb, r21=sa,  r22=ca*cb;
        float dx=-r02, dy=-r12, dz=-r22;
        float inv = rsqrtf(dx*dx+dy*dy+dz*dz);
        dx*=inv; dy*=inv; dz*=inv;
        float ag0=agrid[0], agN=agrid[36], bg0=bgrid[0], bgN=bgrid[25];
        float an = 2.f*(alpha-ag0)/(agN-ag0+1e-8f) - 1.f;
        float bn = 2.f*(beta -bg0)/(bgN-bg0+1e-8f) - 1.f;
        float ai = fminf(fmaxf((an+1.f)*0.5f*36.f, 0.f), 36.f);
        float bi = fminf(fmaxf((bn+1.f)*0.5f*25.f, 0.f), 25.f);
        int a0 = (int)floorf(ai); a0 = a0<0?0:(a0>36?36:a0);
        int b0 = (int)floorf(bi); b0 = b0<0?0:(b0>25?25:b0);
        int a1 = a0+1>36?36:a0+1;
        int b1 = b0+1>25?25:b0+1;
        float fa = ai - (float)a0, fb = bi - (float)b0;
        float v00=lut[a0*26+b0], v01=lut[a0*26+b1], v10=lut[a1*26+b0], v11=lut[a1*26+b1];
        float sd = v00*(1.f-fa)*(1.f-fb) + v01*(1.f-fa)*fb + v10*fa*(1.f-fb) + v11*fa*fb;
        sd = fmaxf(sd, 1.f);
        float pen = sd - shank*0.5f - off;
        float hs = shank*0.5f;
        sst[b*16+0]=r00; sst[b*16+1]=r01; sst[b*16+2]=r02;
        sst[b*16+3]=r10; sst[b*16+4]=r11; sst[b*16+5]=r12;
        sst[b*16+6]=r20; sst[b*16+7]=r21; sst[b*16+8]=r22;
        sst[b*16+9]  = start_loc[0] + dx*pen;
        sst[b*16+10] = start_loc[1] + dy*pen;
        sst[b*16+11] = start_loc[2] + dz*pen;
        sst[b*16+12] = shank;
        sst[b*16+13] = fabsf(r00)*1.8f + fabsf(r01)*1.8f + fabsf(r02)*hs;
        sst[b*16+14] = fabsf(r10)*1.8f + fabsf(r11)*1.8f + fabsf(r12)*hs;
        sst[b*16+15] = fabsf(r20)*1.8f + fabsf(r21)*1.8f + fabsf(r22)*hs;
    }
}

// 72 blocks: g<40 -> AABB cull + ballot compaction of 256 v1 points each;
// g>=40 -> electrode positions (EPOS); g==40 inits WS_MAX.
// Cull: survive iff dist^2(point, AABB_b) <= 90 (dropped weights <= e^-20).
__global__ __launch_bounds__(256) void k_cull(const float* __restrict__ params,
                                              const float* __restrict__ start_loc,
                                              const float* __restrict__ lut,
                                              const float* __restrict__ agrid,
                                              const float* __restrict__ bgrid,
                                              const float* __restrict__ v1_pos,
                                              const float* __restrict__ v1_prf,
                                              const float* __restrict__ tmpl,
                                              float* __restrict__ ws) {
    __shared__ float sst[NB*16];
    __shared__ int   lcnt[NB];
    __shared__ float vpos[768];
    __shared__ float vprf[768];
    int g = blockIdx.x, t = threadIdx.x;
    batch_setup(params, start_loc, lut, agrid, bgrid, sst, t);
    const float C = -0.32059889797532524f;   // -log2(e)/4.5
    if (g >= NSEG) {
        if (g == NSEG && t < NB) ws[WS_MAX + t] = 0.f;
        __syncthreads();
        int v = (g - NSEG)*256 + t;
        float4* ep = (float4*)(ws + WS_EPOS);
        if (v < NB*NN) {
            int b = v/1000, n = v - b*1000;
            const float* st = sst + b*16;
            float gx = tmpl[n*3]-1.8f, gy = tmpl[n*3+1]-1.8f;
            float gz = (tmpl[n*3+2]-0.5f)*st[12];
            float px = st[0]*gx + st[1]*gy + st[2]*gz + st[9];
            float py = st[3]*gx + st[4]*gy + st[5]*gz + st[10];
            float pz = st[6]*gx + st[7]*gy + st[8]*gz + st[11];
            ep[v] = make_float4(px, py, pz, C*(px*px+py*py+pz*pz));
        } else {
            ep[v] = make_float4(0.f, 0.f, 0.f, -1e30f);
        }
        return;
    }
    if (t < NB) lcnt[t] = 0;
    #pragma unroll
    for (int k = 0; k < 3; ++k) {
        int i = k*256 + t;
        int gi = g*768 + i;
        vpos[i] = (gi < NV*3) ? v1_pos[gi] : 0.f;
        vprf[i] = (gi < NV*3) ? v1_prf[gi] : 0.f;
    }
    __syncthreads();
    int v = g*256 + t;
    bool valid = v < NV;
    float x = vpos[t*3], y = vpos[t*3+1], z = vpos[t*3+2];
    float pol = vprf[t*3], ecc = vprf[t*3+1];
    float4 payload = make_float4(-2.f*C*x, -2.f*C*y, -2.f*C*z, C*(x*x+y*y+z*z));
    int lane = t & 63;
    float4* cpos = (float4*)(ws + WS_CPOS);
    float2* cprf = (float2*)(ws + WS_CPRF);
    #pragma unroll
    for (int b = 0; b < NB; ++b) {
        const float* st = sst + b*16;
        float dxc = fmaxf(fabsf(x - st[9])  - st[13], 0.f);
        float dyc = fmaxf(fabsf(y - st[10]) - st[14], 0.f);
        float dzc = fmaxf(fabsf(z - st[11]) - st[15], 0.f);
        bool pred = valid && (dxc*dxc + dyc*dyc + dzc*dzc <= 90.f);
        unsigned long long m = __ballot(pred);
        int base = 0;
        if (lane == 0) base = atomicAdd(&lcnt[b], (int)__popcll(m));
        base = __shfl(base, 0, 64);
        if (pred) {
            int my = base + (int)__popcll(m & ((1ull << lane) - 1ull));
            int slot = b*10240 + g*SEGCAP + my;      // my < 256 structural
            cpos[slot] = payload;
            cprf[slot] = make_float2(pol, ecc);
        }
    }
    __syncthreads();
    if (t < NB) ((int*)(ws + WS_CNT))[g*NB + t] = lcnt[t];
}

// Soft-match over compacted survivors. 160 blocks = 8 b x 20 super-segments
// (2 source segments, <=512 survivors staged once); 4 electrodes/thread
// (4 independent exp2 chains -> good ILP, half the staging of the 320-block
// version, grid fits one scheduling round).
__global__ __launch_bounds__(256) void k_match(float* __restrict__ ws) {
    __shared__ float4 sq[2*SEGCAP];
    __shared__ float2 spe[2*SEGCAP];
    int g = blockIdx.x, t = threadIdx.x;
    int b = g / NSEG2, qp = g - b*NSEG2;
    int q0 = qp*2, q1 = q0 + 1;
    const int* cnt = (const int*)(ws + WS_CNT);
    int c0 = cnt[q0*NB + b], c1 = cnt[q1*NB + b];
    const float4* cpos = (const float4*)(ws + WS_CPOS);
    const float2* cprf = (const float2*)(ws + WS_CPRF);
    if (t < c0) {
        sq[t]  = cpos[b*10240 + q0*SEGCAP + t];
        spe[t] = cprf[b*10240 + q0*SEGCAP + t];
    }
    if (t < c1) {
        sq[c0 + t]  = cpos[b*10240 + q1*SEGCAP + t];
        spe[c0 + t] = cprf[b*10240 + q1*SEGCAP + t];
    }
    __syncthreads();
    int cq = c0 + c1;
    const float4* ep = (const float4*)(ws + WS_EPOS);
    float4 P0 = ep[b*NN + t];                 // t < 1000 guaranteed? t<256 yes
    float4 P1 = (t+256 < NN) ? ep[b*NN + t+256] : make_float4(0.f,0.f,0.f,-1e30f);
    float4 P2 = (t+512 < NN) ? ep[b*NN + t+512] : make_float4(0.f,0.f,0.f,-1e30f);
    float4 P3 = (t+768 < NN) ? ep[b*NN + t+768] : make_float4(0.f,0.f,0.f,-1e30f);
    float sw0=0.f,sp0=0.f,se0=0.f, sw1=0.f,sp1=0.f,se1=0.f;
    float sw2=0.f,sp2=0.f,se2=0.f, sw3=0.f,sp3=0.f,se3=0.f;
    #pragma unroll 2
    for (int i = 0; i < cq; ++i) {
        float4 qq = sq[i];
        float2 pe = spe[i];
        float a0 = fmaf(qq.x, P0.x, fmaf(qq.y, P0.y, fmaf(qq.z, P0.z, P0.w + qq.w)));
        float w0 = __builtin_amdgcn_exp2f(a0);
        sw0 += w0; sp0 = fmaf(w0, pe.x, sp0); se0 = fmaf(w0, pe.y, se0);
        float a1 = fmaf(qq.x, P1.x, fmaf(qq.y, P1.y, fmaf(qq.z, P1.z, P1.w + qq.w)));
        float w1 = __builtin_amdgcn_exp2f(a1);
        sw1 += w1; sp1 = fmaf(w1, pe.x, sp1); se1 = fmaf(w1, pe.y, se1);
        float a2 = fmaf(qq.x, P2.x, fmaf(qq.y, P2.y, fmaf(qq.z, P2.z, P2.w + qq.w)));
        float w2 = __builtin_amdgcn_exp2f(a2);
        sw2 += w2; sp2 = fmaf(w2, pe.x, sp2); se2 = fmaf(w2, pe.y, se2);
        float a3 = fmaf(qq.x, P3.x, fmaf(qq.y, P3.y, fmaf(qq.z, P3.z, P3.w + qq.w)));
        float w3 = __builtin_amdgcn_exp2f(a3);
        sw3 += w3; sp3 = fmaf(w3, pe.x, sp3); se3 = fmaf(w3, pe.y, se3);
    }
    float4* part = (float4*)(ws + WS_PART);
    int baseq = (b*NSEG2 + qp)*NEB;
    part[baseq + t]       = make_float4(sw0, sp0, se0, 0.f);
    part[baseq + t + 256] = make_float4(sw1, sp1, se1, 0.f);
    part[baseq + t + 512] = make_float4(sw2, sp2, se2, 0.f);
    part[baseq + t + 768] = make_float4(sw3, sp3, se3, 0.f);
}

// Fused reduce + params + electrode-parallel region render.
// 128 blocks = 8 b x 16 eblocks of 64 electrodes. Phase A: reduce this
// block's 64 electrodes over 20 super-segment partials, compute render
// params in LDS (no PAR round-trip). Phase B: render 8x8 windows
// (d2<=12.25 truncation, verified) into a private 80x80 LDS region;
// write one partial region per block.
__global__ __launch_bounds__(256) void k_render(const float* __restrict__ logits,
                                                float* __restrict__ ws) {
    __shared__ float reg[RPX];
    __shared__ float4 red[4][64];
    __shared__ float4 spar[64];
    int g = blockIdx.x, t = threadIdx.x, lane = t & 63, w = t >> 6;
    int b = g >> 4, eb = g & 15, E0 = eb*64;
    for (int i = t; i < RPX; i += 256) reg[i] = 0.f;
    // Phase A: partial reduce (same decomposition as old k_params)
    const float4* part = (const float4*)(ws + WS_PART);
    int el = E0 + lane;
    {
        float sw = 0.f, sp = 0.f, se = 0.f;
        #pragma unroll
        for (int i = 0; i < 5; ++i) {
            float4 p = part[(b*NSEG2 + (w + i*4))*NEB + el];
            sw += p.x; sp += p.y; se += p.z;
        }
        red[w][lane] = make_float4(sw, sp, se, 0.f);
    }
    __syncthreads();
    if (w == 0) {
        float4 a = red[0][lane], b4 = red[1][lane], c4 = red[2][lane], d4 = red[3][lane];
        float sw = (a.x+b4.x) + (c4.x+d4.x);
        float sp = (a.y+b4.y) + (c4.y+d4.y);
        float se = (a.z+b4.z) + (c4.z+d4.z);
        float denom = sw + 1e-8f;
        float pol = sp/denom, eccv = se/denom;
        float validity = fminf(sw, 1.f);
        int n = E0 + lane;
        float lg = (n < NN) ? logits[b*NN + n] : 0.f;
        float prob = 1.f/(1.f + __expf(-lg));
        float wgt = (n < NN) ? prob * validity : 0.f;
        float ang = pol * 0.017453292519943295f;
        float m1 = 17.3f*(1.f/(eccv+0.75f) - 1.f/(eccv+120.f));
        float minv = 1.f/(fabsf(m1)+1e-8f);
        float sig  = 0.3849001794597506f * minv * 0.5f;   // sqrt(100/675)*m_inv/2
        const float scl = 256.f/90.f;
        float s = fmaxf(sig*scl, 1.f);
        float invden = 1.f/(s*s + 1e-8f);
        spar[lane] = make_float4(eccv*__cosf(ang)*scl + 128.f,
                                 eccv*__sinf(ang)*scl + 128.f, invden, wgt);
    }
    __syncthreads();
    // Phase B: render
    int ix = lane & 7, iy = lane >> 3;       // 8x8 window, one wave per electrode
    #pragma unroll
    for (int k = 0; k < 16; ++k) {
        float4 P = spar[k*4 + w];
        if (P.w <= 0.f) continue;            // wave-uniform
        int fx = (int)floorf(P.x), fy = (int)floorf(P.y);
        int X = fx - 3 + ix, Y = fy - 3 + iy;
        int xl = X - RB0, yl = Y - RB0;
        float dx = (float)X - P.x, dy = (float)Y - P.y;
        float d2 = dx*dx + dy*dy;
        if ((unsigned)xl < RSZ && (unsigned)yl < RSZ && d2 <= 12.25f) {
            atomicAdd(&reg[xl*RSZ + yl], P.w * __expf(-d2 * P.z));
        }
    }
    __syncthreads();
    float4* dst = (float4*)(ws + WS_RPART) + g*(RPX/4);
    const float4* src = (const float4*)reg;
    #pragma unroll
    for (int i = 0; i < 7; ++i) {
        int idx = i*256 + t;
        if (idx < RPX/4) dst[idx] = src[idx];
    }
}

// Sum 16 partials per (b,px), write region sum, per-b atomicMax.
// 200 blocks = 8 b x 25 (256 px each; 25*256 == RPX).
__global__ __launch_bounds__(256) void k_sum(float* __restrict__ ws) {
    __shared__ float mred[4];
    int g = blockIdx.x, t = threadIdx.x, lane = t & 63, w = t >> 6;
    int b = g / 25, p25 = g - b*25;
    int px = p25*256 + t;
    const float* rp = ws + WS_RPART + (b*NEBLK)*RPX + px;
    float s = 0.f;
    #pragma unroll
    for (int p = 0; p < NEBLK; ++p) s += rp[p*RPX];
    ws[WS_RSUM + b*RPX + px] = s;
    float mx = s;
    #pragma unroll
    for (int s2 = 32; s2 >= 1; s2 >>= 1) mx = fmaxf(mx, __shfl_xor(mx, s2, 64));
    if (lane == 0) mred[w] = mx;
    __syncthreads();
    if (t == 0) {
        mx = fmaxf(fmaxf(mred[0], mred[1]), fmaxf(mred[2], mred[3]));
        atomicMax((unsigned int*)(ws + WS_MAX + b), __float_as_uint(mx));
    }
}

// Full output: out[b,r,c] = rot90(region)/max, zeros outside.
// out[b,r,c] = raw[b,c,255-r]/max ; raw[Y,X] = regsum[xl=X-88][yl=Y-88].
// 512 blocks x 256 threads, one float4 (4 consecutive c) per thread.
__global__ __launch_bounds__(256) void k_out(const float* __restrict__ ws,
                                             float* __restrict__ out) {
    int o = blockIdx.x*256 + threadIdx.x;    // 131072 float4
    int b = o >> 14, rem = o & 16383;
    int r = rem >> 6, c4 = (rem & 63) << 2;
    float inv = 1.f/(ws[WS_MAX + b] + 1e-8f);
    float4 v = make_float4(0.f, 0.f, 0.f, 0.f);
    int xl = 167 - r;                        // X = 255-r; xl = X-RB0
    if ((unsigned)xl < RSZ) {
        const float* rs = ws + WS_RSUM + b*RPX + xl*RSZ;
        float* vv = &v.x;
        #pragma unroll
        for (int j = 0; j < 4; ++j) {
            int yl = c4 + j - RB0;           // Y = c; yl = Y-RB0
            if ((unsigned)yl < RSZ) vv[j] = rs[yl]*inv;
        }
    }
    ((float4*)out)[o] = v;
}

extern "C" void kernel_launch(void* const* d_in, const int* in_sizes, int n_in,
                              void* d_out, int out_size, void* d_ws, size_t ws_size,
                              hipStream_t stream) {
    const float* params    = (const float*)d_in[0];
    const float* logits    = (const float*)d_in[1];
    const float* v1_pos    = (const float*)d_in[2];
    const float* v1_prf    = (const float*)d_in[3];
    const float* start_loc = (const float*)d_in[4];
    const float* lut       = (const float*)d_in[5];
    const float* agrid     = (const float*)d_in[6];
    const float* bgrid     = (const float*)d_in[7];
    const float* tmpl      = (const float*)d_in[8];
    float* ws  = (float*)d_ws;
    float* out = (float*)d_out;

    k_cull  <<<72,  256, 0, stream>>>(params, start_loc, lut, agrid, bgrid,
                                      v1_pos, v1_prf, tmpl, ws);
    k_match <<<160, 256, 0, stream>>>(ws);
    k_render<<<128, 256, 0, stream>>>(logits, ws);
    k_sum   <<<200, 256, 0, stream>>>(ws);
    k_out   <<<512, 256, 0, stream>>>(ws, out);
}

// Round 5
// 98.561 us; speedup vs baseline: 1.0511x; 1.0511x over previous
//
#include <hip/hip_runtime.h>
#include <math.h>

#define NB 8
#define NN 1000
#define NV 10000
#define NSEG2 20                 // super-segments (512 v1 points each)
#define NEB 1024                 // padded electrodes per batch

// render region: all contributions provably in X,Y in [90,166]
// (ecc<=12 -> |c-128|<=34.14 -> f in [93,162] -> X in [90,166])
#define RB0 88                   // region origin
#define RSZ 80                   // region size (80x80)
#define RPX 6400                 // RSZ*RSZ

// ---- workspace layout (float offsets), ~2.8 MB ----
#define WS_PART 0                // 8 b x 20 qp x 1024 elec x float4 partials
#define WS_RSUM 655360           // 8 x 6400 region sums (atomic-accumulated)
#define WS_MAX  706560           // 8 per-b max

// Single-batch setup -> sst[16]: R[9], center[3], shank, halfext[3].
__device__ __forceinline__ void batch_setup_one(const float* params, const float* start_loc,
                                                const float* lut, const float* agrid,
                                                const float* bgrid, float* sst, int b) {
    float alpha = params[b*4+0], beta = params[b*4+1];
    float off   = params[b*4+2], shank = params[b*4+3];
    const float D2R = 0.017453292519943295f;
    float a = alpha*D2R, bb = beta*D2R;
    float ca = cosf(a), sa = sinf(a), cb = cosf(bb), sb = sinf(bb);
    float r00=cb,     r01=0.f, r02=sb;
    float r10=sa*sb,  r11=ca,  r12=-sa*cb;
    float r20=-ca*sb, r21=sa,  r22=ca*cb;
    float dx=-r02, dy=-r12, dz=-r22;
    float inv = rsqrtf(dx*dx+dy*dy+dz*dz);
    dx*=inv; dy*=inv; dz*=inv;
    float ag0=agrid[0], agN=agrid[36], bg0=bgrid[0], bgN=bgrid[25];
    float an = 2.f*(alpha-ag0)/(agN-ag0+1e-8f) - 1.f;
    float bn = 2.f*(beta -bg0)/(bgN-bg0+1e-8f) - 1.f;
    float ai = fminf(fmaxf((an+1.f)*0.5f*36.f, 0.f), 36.f);
    float bi = fminf(fmaxf((bn+1.f)*0.5f*25.f, 0.f), 25.f);
    int a0 = (int)floorf(ai); a0 = a0<0?0:(a0>36?36:a0);
    int b0 = (int)floorf(bi); b0 = b0<0?0:(b0>25?25:b0);
    int a1 = a0+1>36?36:a0+1;
    int b1 = b0+1>25?25:b0+1;
    float fa = ai - (float)a0, fb = bi - (float)b0;
    float v00=lut[a0*26+b0], v01=lut[a0*26+b1], v10=lut[a1*26+b0], v11=lut[a1*26+b1];
    float sd = v00*(1.f-fa)*(1.f-fb) + v01*(1.f-fa)*fb + v10*fa*(1.f-fb) + v11*fa*fb;
    sd = fmaxf(sd, 1.f);
    float pen = sd - shank*0.5f - off;
    float hs = shank*0.5f;
    sst[0]=r00; sst[1]=r01; sst[2]=r02;
    sst[3]=r10; sst[4]=r11; sst[5]=r12;
    sst[6]=r20; sst[7]=r21; sst[8]=r22;
    sst[9]  = start_loc[0] + dx*pen;
    sst[10] = start_loc[1] + dy*pen;
    sst[11] = start_loc[2] + dz*pen;
    sst[12] = shank;
    sst[13] = fabsf(r00)*1.8f + fabsf(r01)*1.8f + fabsf(r02)*hs;
    sst[14] = fabsf(r10)*1.8f + fabsf(r11)*1.8f + fabsf(r12)*hs;
    sst[15] = fabsf(r20)*1.8f + fabsf(r21)*1.8f + fabsf(r22)*hs;
}

// Fused cull + soft-match. 160 blocks = 8 b x 20 super-segments (512 v1
// points each). Per block: setup batch b (thread 0), cull own 512 points
// against batch-b AABB (survive iff dist^2 <= 90; dropped weights <= e^-20,
// map error ~1e-4 << tol) with ballot compaction straight into LDS (no
// global cull intermediates), compute own 4 electrode fragments from the
// template, run the match loop, write PART. Also zeroes RSUM, inits MAX.
__global__ __launch_bounds__(256) void k_match(const float* __restrict__ params,
                                               const float* __restrict__ start_loc,
                                               const float* __restrict__ lut,
                                               const float* __restrict__ agrid,
                                               const float* __restrict__ bgrid,
                                               const float* __restrict__ v1_pos,
                                               const float* __restrict__ v1_prf,
                                               const float* __restrict__ tmpl,
                                               float* __restrict__ ws) {
    __shared__ float4 sq[512];
    __shared__ float2 spe[512];
    __shared__ float  sst[16];
    __shared__ int    scnt;
    int g = blockIdx.x, t = threadIdx.x, lane = t & 63;
    int b = g / NSEG2, qp = g - b*NSEG2;
    // zero RSUM (51200 floats over 40960 threads) + init MAX
    for (int i = g*256 + t; i < NB*RPX; i += 160*256) ws[WS_RSUM + i] = 0.f;
    if (g == 0 && t < NB) ws[WS_MAX + t] = 0.f;
    if (t == 0) { batch_setup_one(params, start_loc, lut, agrid, bgrid, sst, b); scnt = 0; }
    __syncthreads();
    const float C = -0.32059889797532524f;   // -log2(e)/4.5
    // ---- cull two points per thread (segment range [qp*512, qp*512+512)) ----
    #pragma unroll
    for (int h = 0; h < 2; ++h) {
        int v = qp*512 + h*256 + t;
        bool valid = v < NV;
        float x=0.f, y=0.f, z=0.f, pol=0.f, ecc=0.f;
        if (valid) {
            x = v1_pos[v*3]; y = v1_pos[v*3+1]; z = v1_pos[v*3+2];
            pol = v1_prf[v*3]; ecc = v1_prf[v*3+1];
        }
        float dxc = fmaxf(fabsf(x - sst[9])  - sst[13], 0.f);
        float dyc = fmaxf(fabsf(y - sst[10]) - sst[14], 0.f);
        float dzc = fmaxf(fabsf(z - sst[11]) - sst[15], 0.f);
        bool pred = valid && (dxc*dxc + dyc*dyc + dzc*dzc <= 90.f);
        unsigned long long m = __ballot(pred);
        int base = 0;
        if (lane == 0) base = atomicAdd(&scnt, (int)__popcll(m));
        base = __shfl(base, 0, 64);
        if (pred) {
            int idx = base + (int)__popcll(m & ((1ull << lane) - 1ull));
            sq[idx]  = make_float4(-2.f*C*x, -2.f*C*y, -2.f*C*z, C*(x*x+y*y+z*z));
            spe[idx] = make_float2(pol, ecc);
        }
    }
    // ---- electrode fragments: 4 per thread, computed from template ----
    float4 P[4];
    #pragma unroll
    for (int j = 0; j < 4; ++j) {
        int n = t + j*256;
        if (n < NN) {
            float gx = tmpl[n*3]-1.8f, gy = tmpl[n*3+1]-1.8f;
            float gz = (tmpl[n*3+2]-0.5f)*sst[12];
            float px = sst[0]*gx + sst[1]*gy + sst[2]*gz + sst[9];
            float py = sst[3]*gx + sst[4]*gy + sst[5]*gz + sst[10];
            float pz = sst[6]*gx + sst[7]*gy + sst[8]*gz + sst[11];
            P[j] = make_float4(px, py, pz, C*(px*px+py*py+pz*pz));
        } else {
            P[j] = make_float4(0.f, 0.f, 0.f, -1e30f);
        }
    }
    __syncthreads();
    int cq = scnt;
    float sw0=0.f,sp0=0.f,se0=0.f, sw1=0.f,sp1=0.f,se1=0.f;
    float sw2=0.f,sp2=0.f,se2=0.f, sw3=0.f,sp3=0.f,se3=0.f;
    #pragma unroll 2
    for (int i = 0; i < cq; ++i) {
        float4 qq = sq[i];
        float2 pe = spe[i];
        float a0 = fmaf(qq.x, P[0].x, fmaf(qq.y, P[0].y, fmaf(qq.z, P[0].z, P[0].w + qq.w)));
        float w0 = __builtin_amdgcn_exp2f(a0);
        sw0 += w0; sp0 = fmaf(w0, pe.x, sp0); se0 = fmaf(w0, pe.y, se0);
        float a1 = fmaf(qq.x, P[1].x, fmaf(qq.y, P[1].y, fmaf(qq.z, P[1].z, P[1].w + qq.w)));
        float w1 = __builtin_amdgcn_exp2f(a1);
        sw1 += w1; sp1 = fmaf(w1, pe.x, sp1); se1 = fmaf(w1, pe.y, se1);
        float a2 = fmaf(qq.x, P[2].x, fmaf(qq.y, P[2].y, fmaf(qq.z, P[2].z, P[2].w + qq.w)));
        float w2 = __builtin_amdgcn_exp2f(a2);
        sw2 += w2; sp2 = fmaf(w2, pe.x, sp2); se2 = fmaf(w2, pe.y, se2);
        float a3 = fmaf(qq.x, P[3].x, fmaf(qq.y, P[3].y, fmaf(qq.z, P[3].z, P[3].w + qq.w)));
        float w3 = __builtin_amdgcn_exp2f(a3);
        sw3 += w3; sp3 = fmaf(w3, pe.x, sp3); se3 = fmaf(w3, pe.y, se3);
    }
    float4* part = (float4*)(ws + WS_PART);
    int baseq = (b*NSEG2 + qp)*NEB;
    part[baseq + t]       = make_float4(sw0, sp0, se0, 0.f);
    part[baseq + t + 256] = make_float4(sw1, sp1, se1, 0.f);
    part[baseq + t + 512] = make_float4(sw2, sp2, se2, 0.f);
    part[baseq + t + 768] = make_float4(sw3, sp3, se3, 0.f);
}

// Fused reduce + params + render + global accumulate + max.
// 128 blocks = 8 b x 16 eblocks of 64 electrodes. Phase A: reduce this
// block's 64 electrodes over 20 super-segment partials, render params in
// LDS. Phase B: render 8x8 windows (d2<=12.25 truncation, verified) into a
// private 80x80 LDS region. Phase C: atomicAdd nonzero pixels into global
// RSUM; max trick (exact, harness-verified in the 4-kernel version):
// atomicAdd returns old; the LAST adder to a pixel observes old+val ==
// final, every observation <= final -> max over observed, 0-init, is the
// true max. Pixels nobody touches stay 0 and can't exceed the max.
__global__ __launch_bounds__(256) void k_render(const float* __restrict__ logits,
                                                float* __restrict__ ws) {
    __shared__ float reg[RPX];
    __shared__ float4 red[4][64];
    __shared__ float4 spar[64];
    __shared__ float mred[4];
    int g = blockIdx.x, t = threadIdx.x, lane = t & 63, w = t >> 6;
    int b = g >> 4, eb = g & 15, E0 = eb*64;
    for (int i = t; i < RPX; i += 256) reg[i] = 0.f;
    // Phase A
    const float4* part = (const float4*)(ws + WS_PART);
    int el = E0 + lane;
    {
        float sw = 0.f, sp = 0.f, se = 0.f;
        #pragma unroll
        for (int i = 0; i < 5; ++i) {
            float4 p = part[(b*NSEG2 + (w + i*4))*NEB + el];
            sw += p.x; sp += p.y; se += p.z;
        }
        red[w][lane] = make_float4(sw, sp, se, 0.f);
    }
    __syncthreads();
    if (w == 0) {
        float4 a = red[0][lane], b4 = red[1][lane], c4 = red[2][lane], d4 = red[3][lane];
        float sw = (a.x+b4.x) + (c4.x+d4.x);
        float sp = (a.y+b4.y) + (c4.y+d4.y);
        float se = (a.z+b4.z) + (c4.z+d4.z);
        float denom = sw + 1e-8f;
        float pol = sp/denom, eccv = se/denom;
        float validity = fminf(sw, 1.f);
        int n = E0 + lane;
        float lg = (n < NN) ? logits[b*NN + n] : 0.f;
        float prob = 1.f/(1.f + __expf(-lg));
        float wgt = (n < NN) ? prob * validity : 0.f;
        float ang = pol * 0.017453292519943295f;
        float m1 = 17.3f*(1.f/(eccv+0.75f) - 1.f/(eccv+120.f));
        float minv = 1.f/(fabsf(m1)+1e-8f);
        float sig  = 0.3849001794597506f * minv * 0.5f;   // sqrt(100/675)*m_inv/2
        const float scl = 256.f/90.f;
        float s = fmaxf(sig*scl, 1.f);
        float invden = 1.f/(s*s + 1e-8f);
        spar[lane] = make_float4(eccv*__cosf(ang)*scl + 128.f,
                                 eccv*__sinf(ang)*scl + 128.f, invden, wgt);
    }
    __syncthreads();
    // Phase B
    int ix = lane & 7, iy = lane >> 3;       // 8x8 window, one wave per electrode
    #pragma unroll
    for (int k = 0; k < 16; ++k) {
        float4 Pp = spar[k*4 + w];
        if (Pp.w <= 0.f) continue;           // wave-uniform
        int fx = (int)floorf(Pp.x), fy = (int)floorf(Pp.y);
        int X = fx - 3 + ix, Y = fy - 3 + iy;
        int xl = X - RB0, yl = Y - RB0;
        float dx = (float)X - Pp.x, dy = (float)Y - Pp.y;
        float d2 = dx*dx + dy*dy;
        if ((unsigned)xl < RSZ && (unsigned)yl < RSZ && d2 <= 12.25f) {
            atomicAdd(&reg[xl*RSZ + yl], Pp.w * __expf(-d2 * Pp.z));
        }
    }
    __syncthreads();
    // Phase C: accumulate nonzero px into global RSUM + exact max trick
    float* rsum = ws + WS_RSUM + b*RPX;
    float mx = 0.f;
    for (int i = t; i < RPX; i += 256) {
        float v = reg[i];
        if (v > 0.f) {
            float old = atomicAdd(&rsum[i], v);
            mx = fmaxf(mx, old + v);
        }
    }
    #pragma unroll
    for (int s2 = 32; s2 >= 1; s2 >>= 1) mx = fmaxf(mx, __shfl_xor(mx, s2, 64));
    if (lane == 0) mred[w] = mx;
    __syncthreads();
    if (t == 0) {
        mx = fmaxf(fmaxf(mred[0], mred[1]), fmaxf(mred[2], mred[3]));
        atomicMax((unsigned int*)(ws + WS_MAX + b), __float_as_uint(mx));
    }
}

// Full output: out[b,r,c] = rot90(region)/max, zeros outside.
// out[b,r,c] = raw[b,c,255-r]/max ; raw[Y,X] = rsum[xl=X-88][yl=Y-88].
// 512 blocks x 256 threads, one float4 (4 consecutive c) per thread.
__global__ __launch_bounds__(256) void k_out(const float* __restrict__ ws,
                                             float* __restrict__ out) {
    int o = blockIdx.x*256 + threadIdx.x;    // 131072 float4
    int b = o >> 14, rem = o & 16383;
    int r = rem >> 6, c4 = (rem & 63) << 2;
    float inv = 1.f/(ws[WS_MAX + b] + 1e-8f);
    float4 v = make_float4(0.f, 0.f, 0.f, 0.f);
    int xl = 167 - r;                        // X = 255-r; xl = X-RB0
    if ((unsigned)xl < RSZ) {
        const float* rs = ws + WS_RSUM + b*RPX + xl*RSZ;
        float* vv = &v.x;
        #pragma unroll
        for (int j = 0; j < 4; ++j) {
            int yl = c4 + j - RB0;           // Y = c; yl = Y-RB0
            if ((unsigned)yl < RSZ) vv[j] = rs[yl]*inv;
        }
    }
    ((float4*)out)[o] = v;
}

extern "C" void kernel_launch(void* const* d_in, const int* in_sizes, int n_in,
                              void* d_out, int out_size, void* d_ws, size_t ws_size,
                              hipStream_t stream) {
    const float* params    = (const float*)d_in[0];
    const float* logits    = (const float*)d_in[1];
    const float* v1_pos    = (const float*)d_in[2];
    const float* v1_prf    = (const float*)d_in[3];
    const float* start_loc = (const float*)d_in[4];
    const float* lut       = (const float*)d_in[5];
    const float* agrid     = (const float*)d_in[6];
    const float* bgrid     = (const float*)d_in[7];
    const float* tmpl      = (const float*)d_in[8];
    float* ws  = (float*)d_ws;
    float* out = (float*)d_out;

    k_match <<<160, 256, 0, stream>>>(params, start_loc, lut, agrid, bgrid,
                                      v1_pos, v1_prf, tmpl, ws);
    k_render<<<128, 256, 0, stream>>>(logits, ws);
    k_out   <<<512, 256, 0, stream>>>(ws, out);
}